// Round 1
// baseline (319.722 us; speedup 1.0000x reference)
//
#include <hip/hip_runtime.h>
#include <math.h>

#define N_PRED  12
#define N_DRIFT 2
#define N_DW    3
#define N_NODES 4096
#define BB      128
#define LL      16
#define BN      (BB * N_NODES)   // 524288 pairs
#define TPB     128              // threads (= pairs) per chunk
#define CPB     4                // chunks per block (software pipeline depth)
#define NCHUNK  (BN / TPB)       // 4096 chunks
#define NBLK    (NCHUNK / CPB)   // 1024 blocks -> 4 resident blocks/CU, zero tail
#define XROW    13               // float4 slots per pair row (12 data + 1 pad)

// ---------------------------------------------------------------------------
// Pre-kernel: fold (deform ∘ conv_t) and (deform ∘ conv_n) into dense uniform
// matrices Mt, Mn of shape [48][12]. Unchanged (verified correct).
// ---------------------------------------------------------------------------
__global__ void deform_precompute(const float* __restrict__ offset_t,
                                  const float* __restrict__ offset_n,
                                  const float* __restrict__ conv_t_w,
                                  const float* __restrict__ conv_n_w,
                                  float* __restrict__ Mt,
                                  float* __restrict__ Mn) {
    int t = threadIdx.x;
    if (t >= N_PRED * N_DW * LL) return;      // 576
    int q  = t % N_PRED;
    int kl = t / N_PRED;
    int k  = kl / LL;
    int l  = kl % LL;

    auto coef = [&](const float* off, int c) -> float {
        float pos = tanhf(off[k * N_PRED + c]) * (float)N_DRIFT
                    + (float)(c + N_DRIFT);
        float idf = floorf(pos);
        float fr  = pos - idf;
        int   id  = (int)idf;
        if (l == id)     return 1.0f - fr;
        if (l == id + 1) return fr;
        return 0.0f;
    };

    float mt = 0.0f;
    #pragma unroll
    for (int h = 0; h < 3; ++h) {
        int c = q - 1 + h;
        if (c < 0 || c >= N_PRED) continue;
        mt += conv_t_w[k * 3 + h] * coef(offset_t, c);
    }

    float mn = 0.0f;
    #pragma unroll
    for (int c = 0; c < N_PRED; ++c) {
        mn += conv_n_w[q * (N_PRED * N_DW) + c * N_DW + k] * coef(offset_n, c);
    }

    Mt[kl * N_PRED + q] = mt;
    Mn[kl * N_PRED + q] = mn;
}

// ---------------------------------------------------------------------------
// Main kernel, R3: software-pipelined chunks (T14 async-stage split).
//  - Each block owns CPB=4 consecutive chunks of 128 pairs. Chunk k+1's 12
//    coalesced global_load_dwordx4 are ISSUED right after the post-stage
//    barrier and CONSUMED (reg->LDS) only at the top of the next iteration:
//    ~4K cycles of FMA cover the ~900-cycle HBM latency, so the memory pipe
//    stays busy instead of the 30% duty cycle of the phase-serial R2.
//  - x keeps the verified stride-13 swizzled LDS transpose (conflict-free
//    b128 on both sides).
//  - ctrl/bparam: direct per-thread 48B-row loads (dense across the wave,
//    L1 absorbs line overlap), issued at compute start, hidden under FMAs.
//    Drops cs4 -> LDS = 26624 B.
//  - outputs: direct 3x float4 stores per thread. L2 is writeback with every
//    byte of every line written -> HBM write traffic unchanged; removes the
//    restage barrier from the pipeline.
// ---------------------------------------------------------------------------
__global__ __launch_bounds__(TPB) void deform_main(
        const float* __restrict__ inp,      // (BN, 3, 16)
        const float* __restrict__ ctrl,     // (BN, 12)
        const float* __restrict__ W,        // (12, 12)
        const float* __restrict__ bparam,   // (N_NODES, 12)
        const float* __restrict__ conv_t_b, // (1,)
        const float* __restrict__ conv_n_b, // (12,)
        const float* __restrict__ Mt,       // (48, 12)
        const float* __restrict__ Mn,       // (48, 12)
        float* __restrict__ out) {          // (BN, 12)
    __shared__ float4 xs4[TPB * XROW];      // 26624 B

    const int t      = threadIdx.x;
    const int chunk0 = blockIdx.x * CPB;

    const float4* gin_base = (const float4*)inp;

    // ---- prologue: load chunk 0 into registers ----
    float4 pre[12];
    {
        const float4* gin = gin_base + (size_t)chunk0 * (TPB * 12);
        #pragma unroll
        for (int i = 0; i < 12; ++i) pre[i] = gin[i * TPB + t];
    }

    // hoisted uniform biases (scalar-cached)
    const float ctb = conv_t_b[0];

    #pragma unroll 1
    for (int k = 0; k < CPB; ++k) {
        const int chunk = chunk0 + k;

        // ---- reg -> swizzled LDS (waits on this chunk's loads) ----
        #pragma unroll
        for (int i = 0; i < 12; ++i) {
            int A = i * TPB + t;
            xs4[(A / 12) * XROW + (A % 12)] = pre[i];
        }
        __syncthreads();

        // ---- issue next chunk's loads NOW; consumed next iteration ----
        if (k + 1 < CPB) {
            const float4* gin = gin_base + (size_t)(chunk + 1) * (TPB * 12);
            #pragma unroll
            for (int i = 0; i < 12; ++i) pre[i] = gin[i * TPB + t];
        }

        const int tid = chunk * TPB + t;
        const int n   = tid & (N_NODES - 1);

        // ---- issue ctrl + bparam row loads (48B each, dense across wave);
        //      consumed only at the gate phase ~3K cycles from now ----
        float4 cv[3], bv[3];
        {
            const float4* gct = (const float4*)ctrl + (size_t)tid * 3;
            #pragma unroll
            for (int i = 0; i < 3; ++i) cv[i] = gct[i];
            const float4* gbp = (const float4*)bparam + (size_t)n * 3;
            #pragma unroll
            for (int i = 0; i < 3; ++i) bv[i] = gbp[i];
        }

        // ---- folded matvecs: 1152 FMAs, weights wave-uniform (s_load) ----
        float acct[12], accn[12];
        #pragma unroll
        for (int q = 0; q < N_PRED; ++q) {
            acct[q] = ctb;
            accn[q] = conv_n_b[q];
        }

        #pragma unroll
        for (int c = 0; c < 12; ++c) {
            float4 v = xs4[t * XROW + c];   // conflict-free b128 (13 coprime 8)
            #pragma unroll
            for (int e = 0; e < 4; ++e) {
                float xv = (e == 0) ? v.x : (e == 1) ? v.y : (e == 2) ? v.z : v.w;
                const int kl = 4 * c + e;
                #pragma unroll
                for (int q = 0; q < N_PRED; ++q) {
                    acct[q] = fmaf(Mt[kl * N_PRED + q], xv, acct[q]);
                    accn[q] = fmaf(Mn[kl * N_PRED + q], xv, accn[q]);
                }
            }
        }

        // ---- gate matvec (same accumulation order as R2) ----
        float accg[12];
        const float* bvf = (const float*)bv;
        const float* cvf = (const float*)cv;
        #pragma unroll
        for (int q = 0; q < N_PRED; ++q) accg[q] = bvf[q];
        #pragma unroll
        for (int p = 0; p < N_PRED; ++p) {
            float c = cvf[p];
            #pragma unroll
            for (int q = 0; q < N_PRED; ++q) {
                accg[q] = fmaf(c, W[p * N_PRED + q], accg[q]);
            }
        }

        // ---- sigmoid gate + blend ----
        float4 o4[3];
        float* ov = (float*)o4;
        #pragma unroll
        for (int q = 0; q < N_PRED; ++q) {
            float g = 1.0f / (1.0f + __expf(-accg[q]));
            ov[q] = accn[q] * g + acct[q] * (1.0f - g);
        }

        // ---- direct stores: 48B/thread, dense across wave, L2 merges ----
        float4* gout = (float4*)out + (size_t)tid * 3;
        #pragma unroll
        for (int j = 0; j < 3; ++j) gout[j] = o4[j];

        // all xs4 reads of this chunk complete before next iteration's writes
        __syncthreads();
    }
}

extern "C" void kernel_launch(void* const* d_in, const int* in_sizes, int n_in,
                              void* d_out, int out_size, void* d_ws, size_t ws_size,
                              hipStream_t stream) {
    const float* inp      = (const float*)d_in[0];
    const float* ctrl     = (const float*)d_in[1];
    const float* offset_t = (const float*)d_in[2];
    const float* offset_n = (const float*)d_in[3];
    const float* conv_t_w = (const float*)d_in[4];
    const float* conv_t_b = (const float*)d_in[5];
    const float* conv_n_w = (const float*)d_in[6];
    const float* conv_n_b = (const float*)d_in[7];
    const float* W        = (const float*)d_in[8];
    const float* bparam   = (const float*)d_in[9];
    float* out = (float*)d_out;

    float* Mt = (float*)d_ws;            // 576 floats
    float* Mn = Mt + N_DW * LL * N_PRED; // 576 floats (ws >= 4608 B)

    deform_precompute<<<1, 576, 0, stream>>>(offset_t, offset_n,
                                             conv_t_w, conv_n_w, Mt, Mn);
    deform_main<<<NBLK, TPB, 0, stream>>>(inp, ctrl, W, bparam,
                                          conv_t_b, conv_n_b, Mt, Mn, out);
}

// Round 2
// 299.008 us; speedup vs baseline: 1.0693x; 1.0693x over previous
//
#include <hip/hip_runtime.h>
#include <math.h>

#define N_PRED  12
#define N_DRIFT 2
#define N_DW    3
#define N_NODES 4096
#define BB      128
#define LL      16
#define BN      (BB * N_NODES)   // 524288 pairs
#define TPB     128              // threads (= pairs) per chunk
#define CPB     4                // chunks per block (software pipeline depth)
#define NCHUNK  (BN / TPB)       // 4096 chunks
#define NBLK    (NCHUNK / CPB)   // 1024 blocks = 4 resident/CU, persistent
#define XROW    13               // float4 slots per pair row (12 data + 1 pad)

// ---------------------------------------------------------------------------
// Pre-kernel: fold (deform ∘ conv_t) and (deform ∘ conv_n) into dense uniform
// matrices Mt, Mn of shape [48][12]. Unchanged (verified correct).
// ---------------------------------------------------------------------------
__global__ void deform_precompute(const float* __restrict__ offset_t,
                                  const float* __restrict__ offset_n,
                                  const float* __restrict__ conv_t_w,
                                  const float* __restrict__ conv_n_w,
                                  float* __restrict__ Mt,
                                  float* __restrict__ Mn) {
    int t = threadIdx.x;
    if (t >= N_PRED * N_DW * LL) return;      // 576
    int q  = t % N_PRED;
    int kl = t / N_PRED;
    int k  = kl / LL;
    int l  = kl % LL;

    auto coef = [&](const float* off, int c) -> float {
        float pos = tanhf(off[k * N_PRED + c]) * (float)N_DRIFT
                    + (float)(c + N_DRIFT);
        float idf = floorf(pos);
        float fr  = pos - idf;
        int   id  = (int)idf;
        if (l == id)     return 1.0f - fr;
        if (l == id + 1) return fr;
        return 0.0f;
    };

    float mt = 0.0f;
    #pragma unroll
    for (int h = 0; h < 3; ++h) {
        int c = q - 1 + h;
        if (c < 0 || c >= N_PRED) continue;
        mt += conv_t_w[k * 3 + h] * coef(offset_t, c);
    }

    float mn = 0.0f;
    #pragma unroll
    for (int c = 0; c < N_PRED; ++c) {
        mn += conv_n_w[q * (N_PRED * N_DW) + c * N_DW + k] * coef(offset_n, c);
    }

    Mt[kl * N_PRED + q] = mt;
    Mn[kl * N_PRED + q] = mn;
}

// ---------------------------------------------------------------------------
// Main kernel, R4: R2's verified fully-coalesced IO patterns + R3's software
// pipeline across chunks.
//  R3 post-mortem (counters): direct 48B/thread stores caused 5x WRITE_SIZE
//  (partial-line write amplification) + ~40MB write-allocate refetch. So ALL
//  streaming IO goes through LDS restage again:
//   - x:    coalesced gload -> regs -> swizzled stride-13 LDS (conflict-free)
//   - ctrl: coalesced gload -> regs -> natural stride-3 LDS
//   - out:  regs -> dedicated os4 LDS -> 1KB/instr coalesced stores
//  Pipeline: CPB=4 chunks/block; next chunk's 15 global_load_dwordx4 are
//  issued right after the stage barrier and consumed (reg->LDS) at the top of
//  the next iteration, so ~2900 cycles of FMA cover HBM latency.
//  Dedicated os4 output buffer => only 2 barriers/chunk:
//   B1 (post-stage): orders stage writes vs compute reads; also guarantees
//       (via program order: os4 ds_read data must land before the dependent
//       global_store issues, and every thread is past those stores when it
//       reaches B1) that prior-iter output reads are done before this iter's
//       os4 writes.
//   B2 (post-compute): orders xs4/cs4 reads vs next-iter stage writes, and
//       os4 writes vs coalesced output reads.
//  LDS = 26624 + 6144 + 6144 = 38912 B -> 4 blocks/CU; grid 1024 = exactly
//  4/CU resident for the whole kernel (no churn).
// ---------------------------------------------------------------------------
__global__ __launch_bounds__(TPB) void deform_main(
        const float* __restrict__ inp,      // (BN, 3, 16)
        const float* __restrict__ ctrl,     // (BN, 12)
        const float* __restrict__ W,        // (12, 12)
        const float* __restrict__ bparam,   // (N_NODES, 12)
        const float* __restrict__ conv_t_b, // (1,)
        const float* __restrict__ conv_n_b, // (12,)
        const float* __restrict__ Mt,       // (48, 12)
        const float* __restrict__ Mn,       // (48, 12)
        float* __restrict__ out) {          // (BN, 12)
    __shared__ float4 xs4[TPB * XROW];      // 26624 B
    __shared__ float4 cs4[TPB * 3];         //  6144 B
    __shared__ float4 os4[TPB * 3];         //  6144 B   (38912 total)

    const int t      = threadIdx.x;
    const int chunk0 = blockIdx.x * CPB;

    const float4* gin_base = (const float4*)inp;
    const float4* gct_base = (const float4*)ctrl;

    // ---- prologue: chunk 0 into registers (fully coalesced) ----
    float4 pre_x[12];
    float4 pre_c[3];
    {
        const float4* gin = gin_base + (size_t)chunk0 * (TPB * 12);
        #pragma unroll
        for (int i = 0; i < 12; ++i) pre_x[i] = gin[i * TPB + t];
        const float4* gct = gct_base + (size_t)chunk0 * (TPB * 3);
        #pragma unroll
        for (int i = 0; i < 3; ++i) pre_c[i] = gct[i * TPB + t];
    }

    const float ctb = conv_t_b[0];

    #pragma unroll 1
    for (int k = 0; k < CPB; ++k) {
        const int chunk = chunk0 + k;

        // ---- stage: regs -> LDS (waits on this chunk's loads via reg dep) ----
        #pragma unroll
        for (int i = 0; i < 12; ++i) {
            int A = i * TPB + t;            // chunk-local float4 index
            xs4[(A / 12) * XROW + (A % 12)] = pre_x[i];
        }
        #pragma unroll
        for (int i = 0; i < 3; ++i) {
            cs4[i * TPB + t] = pre_c[i];    // stride-3 natural: conflict-free
        }
        __syncthreads();                    // B1

        // ---- issue next chunk's loads NOW; consumed next iteration ----
        if (k + 1 < CPB) {
            const float4* gin = gin_base + (size_t)(chunk + 1) * (TPB * 12);
            #pragma unroll
            for (int i = 0; i < 12; ++i) pre_x[i] = gin[i * TPB + t];
            const float4* gct = gct_base + (size_t)(chunk + 1) * (TPB * 3);
            #pragma unroll
            for (int i = 0; i < 3; ++i) pre_c[i] = gct[i * TPB + t];
        }

        const int tid = chunk * TPB + t;
        const int n   = tid & (N_NODES - 1);

        // ---- gate accumulator starts at bparam[n] (192 KB, L2-resident) ----
        float accg[12];
        {
            const float* bp = bparam + (size_t)n * N_PRED;
            #pragma unroll
            for (int i = 0; i < 3; ++i) {
                float4 v = *(const float4*)(bp + 4 * i);
                accg[4 * i + 0] = v.x; accg[4 * i + 1] = v.y;
                accg[4 * i + 2] = v.z; accg[4 * i + 3] = v.w;
            }
        }

        // ---- pred_t / pred_n accumulators (biases) ----
        float acct[12], accn[12];
        #pragma unroll
        for (int q = 0; q < N_PRED; ++q) {
            acct[q] = ctb;
            accn[q] = conv_n_b[q];
        }

        // ---- folded matvecs: 1152 FMAs, weights wave-uniform (s_load) ----
        #pragma unroll
        for (int c = 0; c < 12; ++c) {
            float4 v = xs4[t * XROW + c];   // conflict-free b128 (13 coprime 8)
            #pragma unroll
            for (int e = 0; e < 4; ++e) {
                float xv = (e == 0) ? v.x : (e == 1) ? v.y : (e == 2) ? v.z : v.w;
                const int kl = 4 * c + e;
                #pragma unroll
                for (int q = 0; q < N_PRED; ++q) {
                    acct[q] = fmaf(Mt[kl * N_PRED + q], xv, acct[q]);
                    accn[q] = fmaf(Mn[kl * N_PRED + q], xv, accn[q]);
                }
            }
        }

        // ---- gate matvec (ctrl from LDS, stride-3: conflict-free) ----
        float cr[12];
        #pragma unroll
        for (int i = 0; i < 3; ++i) {
            float4 v = cs4[t * 3 + i];
            cr[4 * i + 0] = v.x; cr[4 * i + 1] = v.y;
            cr[4 * i + 2] = v.z; cr[4 * i + 3] = v.w;
        }
        #pragma unroll
        for (int p = 0; p < N_PRED; ++p) {
            float cv = cr[p];
            #pragma unroll
            for (int q = 0; q < N_PRED; ++q) {
                accg[q] = fmaf(cv, W[p * N_PRED + q], accg[q]);
            }
        }

        // ---- sigmoid gate + blend ----
        float4 o4[3];
        float* ov = (float*)o4;
        #pragma unroll
        for (int q = 0; q < N_PRED; ++q) {
            float g = 1.0f / (1.0f + __expf(-accg[q]));
            ov[q] = accn[q] * g + acct[q] * (1.0f - g);
        }

        // ---- restage outputs: own slots (no cross-thread hazard pre-B2) ----
        #pragma unroll
        for (int j = 0; j < 3; ++j) {
            os4[t * 3 + j] = o4[j];         // quad (3t+j)%8: conflict-free
        }
        __syncthreads();                    // B2

        // ---- fully-coalesced 1 KB/instr stores ----
        float4* gout = (float4*)out + (size_t)chunk * (TPB * 3);
        #pragma unroll
        for (int j = 0; j < 3; ++j) {
            int A = j * TPB + t;
            gout[A] = os4[A];
        }
        // next iter's B1 separates these os4 reads from the next os4 writes
    }
}

extern "C" void kernel_launch(void* const* d_in, const int* in_sizes, int n_in,
                              void* d_out, int out_size, void* d_ws, size_t ws_size,
                              hipStream_t stream) {
    const float* inp      = (const float*)d_in[0];
    const float* ctrl     = (const float*)d_in[1];
    const float* offset_t = (const float*)d_in[2];
    const float* offset_n = (const float*)d_in[3];
    const float* conv_t_w = (const float*)d_in[4];
    const float* conv_t_b = (const float*)d_in[5];
    const float* conv_n_w = (const float*)d_in[6];
    const float* conv_n_b = (const float*)d_in[7];
    const float* W        = (const float*)d_in[8];
    const float* bparam   = (const float*)d_in[9];
    float* out = (float*)d_out;

    float* Mt = (float*)d_ws;            // 576 floats
    float* Mn = Mt + N_DW * LL * N_PRED; // 576 floats (ws >= 4608 B)

    deform_precompute<<<1, 576, 0, stream>>>(offset_t, offset_n,
                                             conv_t_w, conv_n_w, Mt, Mn);
    deform_main<<<NBLK, TPB, 0, stream>>>(inp, ctrl, W, bparam,
                                          conv_t_b, conv_n_b, Mt, Mn, out);
}

// Round 3
// 277.809 us; speedup vs baseline: 1.1509x; 1.0763x over previous
//
#include <hip/hip_runtime.h>
#include <math.h>

#define N_PRED  12
#define N_DRIFT 2
#define N_DW    3
#define N_NODES 4096
#define BB      128
#define LL      16
#define BN      (BB * N_NODES)   // 524288 pairs
#define TPB     128              // threads (= pairs) per chunk
#define CPB     8                // chunks per block
#define NCHUNK  (BN / TPB)       // 4096 chunks
#define NBLK    (NCHUNK / CPB)   // 512 blocks = exactly 2/CU, persistent
#define XROW    13               // float4 slots per pair row (12 data + 1 pad)
#define XSLOTS  (TPB * XROW)     // 1664
#define CSLOTS  (TPB * 3)        // 384

// ---------------------------------------------------------------------------
// Pre-kernel: fold (deform ∘ conv_t) and (deform ∘ conv_n) into dense uniform
// matrices Mt, Mn of shape [48][12]. Unchanged (verified correct).
// ---------------------------------------------------------------------------
__global__ void deform_precompute(const float* __restrict__ offset_t,
                                  const float* __restrict__ offset_n,
                                  const float* __restrict__ conv_t_w,
                                  const float* __restrict__ conv_n_w,
                                  float* __restrict__ Mt,
                                  float* __restrict__ Mn) {
    int t = threadIdx.x;
    if (t >= N_PRED * N_DW * LL) return;      // 576
    int q  = t % N_PRED;
    int kl = t / N_PRED;
    int k  = kl / LL;
    int l  = kl % LL;

    auto coef = [&](const float* off, int c) -> float {
        float pos = tanhf(off[k * N_PRED + c]) * (float)N_DRIFT
                    + (float)(c + N_DRIFT);
        float idf = floorf(pos);
        float fr  = pos - idf;
        int   id  = (int)idf;
        if (l == id)     return 1.0f - fr;
        if (l == id + 1) return fr;
        return 0.0f;
    };

    float mt = 0.0f;
    #pragma unroll
    for (int h = 0; h < 3; ++h) {
        int c = q - 1 + h;
        if (c < 0 || c >= N_PRED) continue;
        mt += conv_t_w[k * 3 + h] * coef(offset_t, c);
    }

    float mn = 0.0f;
    #pragma unroll
    for (int c = 0; c < N_PRED; ++c) {
        mn += conv_n_w[q * (N_PRED * N_DW) + c * N_DW + k] * coef(offset_n, c);
    }

    Mt[kl * N_PRED + q] = mt;
    Mn[kl * N_PRED + q] = mn;
}

// ---------------------------------------------------------------------------
// Main kernel, R5: barrier-free wave-private software pipeline with
// global_load_lds double-buffered staging (zero staging VGPRs -> no spills).
//
// R4 post-mortem: reg-held prefetch spilled (VGPR=88 < ~120 live) -> 123 MB
// of scratch writes (WRITE_SIZE 6x). Fix: stage directly global->LDS.
//
//  - x staging: global_load_lds needs lane-linear LDS dest, so the stride-13
//    swizzle is realized by PRE-SWIZZLING the per-lane GLOBAL source address
//    (m173 pattern): slot s holds chunk float4 A(s) = (s/13)*12 + min(s%13,11)
//    (pad slots re-read a neighbor; never read back). Read side is the
//    verified conflict-free xs4[t*13 + c] layout.
//  - every LDS handoff is wave-private (x/ctrl: thread t<64 reads only
//    wave-0-staged slots, etc.; os4 restage below) -> NO barriers at all.
//    Each wave = independent 2-deep pipeline:
//      issue 16 global_load_lds (chunk k+1, buf^1)  [vmcnt-counted]
//      compute chunk k from buf (~3000 cy hides delivery)
//      one asm s_waitcnt vmcnt(0) AFTER compute (2-phase counted template)
//  - os4 restage wave-private: write os4[3t+j], read os4[w*192+j*64+l]
//    (writer u=s/3 is in reader's wave). Same-wave DS ops are in-order and
//    the compiler keeps may-alias DS ops ordered -> no explicit lgkm fence.
//  - __launch_bounds__(TPB,1): occupancy is LDS-bound (71680 B -> 2 blk/CU);
//    free the allocator up to 512 VGPRs so spilling is impossible.
// ---------------------------------------------------------------------------
typedef const __attribute__((address_space(1))) void* gas1_t;
typedef __attribute__((address_space(3))) void* las3_t;

__device__ __forceinline__ void gll16(const void* g, void* lds) {
    __builtin_amdgcn_global_load_lds((gas1_t)g, (las3_t)lds, 16, 0, 0);
}

__global__ __launch_bounds__(TPB, 1) void deform_main(
        const float* __restrict__ inp,      // (BN, 3, 16)
        const float* __restrict__ ctrl,     // (BN, 12)
        const float* __restrict__ W,        // (12, 12)
        const float* __restrict__ bparam,   // (N_NODES, 12)
        const float* __restrict__ conv_t_b, // (1,)
        const float* __restrict__ conv_n_b, // (12,)
        const float* __restrict__ Mt,       // (48, 12)
        const float* __restrict__ Mn,       // (48, 12)
        float* __restrict__ out) {          // (BN, 12)
    __shared__ float4 xs4[2][XSLOTS];       // 53248 B
    __shared__ float4 cs4[2][CSLOTS];       // 12288 B
    __shared__ float4 os4[CSLOTS];          //  6144 B  (71680 total -> 2/CU)

    const int t = threadIdx.x;
    const int l = t & 63;                   // lane
    const int w = t >> 6;                   // wave (0/1)
    const int chunk0 = blockIdx.x * CPB;

    // per-lane pre-swizzled x source byte offsets: slot s -> A(s)*16
    unsigned axb[13];
    #pragma unroll
    for (int j = 0; j < 13; ++j) {
        unsigned s = (unsigned)((13 * w + j) * 64 + l);
        unsigned q = (s * 5042u) >> 16;         // exact s/13 for s < 1664
        unsigned r = s - q * 13u;
        unsigned A = q * 12u + (r < 12u ? r : 11u);
        axb[j] = A * 16u;
    }

    const char* gx_base = (const char*)inp;   // 24576 B per chunk
    const char* gc_base = (const char*)ctrl;  //  6144 B per chunk

    auto STAGE = [&](int b, int chunk) {
        const char* gx = gx_base + (size_t)chunk * 24576;
        #pragma unroll
        for (int j = 0; j < 13; ++j)
            gll16(gx + axb[j], &xs4[b][(13 * w + j) * 64]);
        const char* gc = gc_base + (size_t)chunk * 6144 + (size_t)l * 16;
        #pragma unroll
        for (int j = 0; j < 3; ++j)
            gll16(gc + (3 * w + j) * 1024, &cs4[b][(3 * w + j) * 64]);
    };

    // prologue: stage chunk 0, drain
    STAGE(0, chunk0);
    asm volatile("s_waitcnt vmcnt(0)" ::: "memory");
    __builtin_amdgcn_sched_barrier(0);

    const float ctb = conv_t_b[0];

    #pragma unroll 1
    for (int k = 0; k < CPB; ++k) {
        const int b     = k & 1;
        const int chunk = chunk0 + k;

        // ---- issue next chunk's staging (async, vmcnt-counted) ----
        if (k + 1 < CPB) STAGE(b ^ 1, chunk + 1);
        __builtin_amdgcn_sched_barrier(0);   // pin issue before compute

        const int tid = chunk * TPB + t;
        const int n   = tid & (N_NODES - 1);

        // ---- gate accumulator from bparam[n] (192 KB, L2-resident) ----
        float accg[12];
        {
            const float4* bp = (const float4*)(bparam + (size_t)n * N_PRED);
            #pragma unroll
            for (int i = 0; i < 3; ++i) {
                float4 v = bp[i];
                accg[4*i+0] = v.x; accg[4*i+1] = v.y;
                accg[4*i+2] = v.z; accg[4*i+3] = v.w;
            }
        }

        float acct[12], accn[12];
        #pragma unroll
        for (int q = 0; q < N_PRED; ++q) {
            acct[q] = ctb;
            accn[q] = conv_n_b[q];
        }

        // ---- folded matvecs: 1152 FMAs, weights wave-uniform (s_load) ----
        #pragma unroll
        for (int c = 0; c < 12; ++c) {
            float4 v = xs4[b][t * XROW + c];  // conflict-free b128
            #pragma unroll
            for (int e = 0; e < 4; ++e) {
                float xv = (e == 0) ? v.x : (e == 1) ? v.y : (e == 2) ? v.z : v.w;
                const int kl = 4 * c + e;
                #pragma unroll
                for (int q = 0; q < N_PRED; ++q) {
                    acct[q] = fmaf(Mt[kl * N_PRED + q], xv, acct[q]);
                    accn[q] = fmaf(Mn[kl * N_PRED + q], xv, accn[q]);
                }
            }
        }

        // ---- gate matvec (ctrl from LDS, stride-3: conflict-free) ----
        float cr[12];
        #pragma unroll
        for (int i = 0; i < 3; ++i) {
            float4 v = cs4[b][t * 3 + i];
            cr[4*i+0] = v.x; cr[4*i+1] = v.y;
            cr[4*i+2] = v.z; cr[4*i+3] = v.w;
        }
        #pragma unroll
        for (int p = 0; p < N_PRED; ++p) {
            float cv = cr[p];
            #pragma unroll
            for (int q = 0; q < N_PRED; ++q) {
                accg[q] = fmaf(cv, W[p * N_PRED + q], accg[q]);
            }
        }

        // ---- sigmoid gate + blend ----
        float4 o4[3];
        float* ov = (float*)o4;
        #pragma unroll
        for (int q = 0; q < N_PRED; ++q) {
            float g = 1.0f / (1.0f + __expf(-accg[q]));
            ov[q] = accn[q] * g + acct[q] * (1.0f - g);
        }

        // ---- wave-private output restage -> fully coalesced 1 KB stores ----
        #pragma unroll
        for (int j = 0; j < 3; ++j) {
            os4[t * 3 + j] = o4[j];           // own slots, own wave
        }
        // reader (w,l) reads slots [w*192, w*192+192): written by own wave;
        // same-wave DS ops are in-order -> no fence needed.
        float4* gout = (float4*)out + (size_t)chunk * CSLOTS;
        #pragma unroll
        for (int j = 0; j < 3; ++j) {
            int s = w * 192 + j * 64 + l;     // lane-linear read: conflict-free
            gout[s] = os4[s];                 // 1 KB contiguous per instr
        }

        // ---- 2-phase counted fence: prefetch (+store acks) drained AFTER
        //      compute, so delivery latency was hidden under the FMAs ----
        asm volatile("s_waitcnt vmcnt(0)" ::: "memory");
        __builtin_amdgcn_sched_barrier(0);
    }
}

extern "C" void kernel_launch(void* const* d_in, const int* in_sizes, int n_in,
                              void* d_out, int out_size, void* d_ws, size_t ws_size,
                              hipStream_t stream) {
    const float* inp      = (const float*)d_in[0];
    const float* ctrl     = (const float*)d_in[1];
    const float* offset_t = (const float*)d_in[2];
    const float* offset_n = (const float*)d_in[3];
    const float* conv_t_w = (const float*)d_in[4];
    const float* conv_t_b = (const float*)d_in[5];
    const float* conv_n_w = (const float*)d_in[6];
    const float* conv_n_b = (const float*)d_in[7];
    const float* W        = (const float*)d_in[8];
    const float* bparam   = (const float*)d_in[9];
    float* out = (float*)d_out;

    float* Mt = (float*)d_ws;            // 576 floats
    float* Mn = Mt + N_DW * LL * N_PRED; // 576 floats (ws >= 4608 B)

    deform_precompute<<<1, 576, 0, stream>>>(offset_t, offset_n,
                                             conv_t_w, conv_n_w, Mt, Mn);
    deform_main<<<NBLK, TPB, 0, stream>>>(inp, ctrl, W, bparam,
                                          conv_t_b, conv_n_b, Mt, Mn, out);
}